// Round 9
// baseline (245.407 us; speedup 1.0000x reference)
//
#include <hip/hip_runtime.h>

// LIF neuron over [T, B, C, H, W] = [8, 32, 128, 32, 32] fp32.
// V_new = V + (-V/TAU + x_t); spike = (V_new>=1) - (V_new<=-1); hard reset.
//
// R1-R8 summary: every single-kernel structure (serial, hoisted, fenced,
// 4-chain, raw-asm 8-in-flight) pins at 79-93 us (~3.3 TB/s combined
// read+write), while write-only poison fills run 6.5 TB/s and forced-MLP
// did not raise VALUBusy -> memory system is the cap for MIXED streams,
// not latency. R9: phase separation via compressed intermediate.
//   K1: read x (134 MB), exact LIF chain, pack 32 spikes (2 bit each,
//       o in {-1,0,+1}) into one uint64/thread -> 8 MB to d_ws.
//   K2: read 8 MB packed, expand, NT-store 128 MB fp32 out (fill-like).
// Fallback to best single-pass kernel if ws_size < 8 MB.

#define T_STEPS 8

typedef float vfloat4 __attribute__((ext_vector_type(4)));

struct StepOut { float V; float o; };

__device__ __forceinline__ StepOut lif_step(float V, float x) {
    const float TAU = (float)(5.0 / 3.0);  // fp32, matches np cast
    // Replicate reference op order exactly: neg, IEEE divide, add, add.
    float dv = (-V) / TAU + x;
    float Vn = V + dv;
    float o = (Vn >= 1.0f ? 1.0f : 0.0f) - (Vn <= -1.0f ? 1.0f : 0.0f);
    StepOut r;
    r.o = o;
    r.V = (o == 0.0f) ? Vn : 0.0f;  // o is exactly -1/0/+1
    return r;
}

__device__ __forceinline__ unsigned enc(float o) {
    // exact: o is one of {-1.f, 0.f, 1.f}
    return (o == 1.0f) ? 1u : ((o == -1.0f) ? 2u : 0u);
}

__device__ __forceinline__ float dec(unsigned c) {
    return (c == 1u) ? 1.0f : ((c == 2u) ? -1.0f : 0.0f);
}

#define ASM_LOAD(dst, addr)                                        \
    asm volatile("global_load_dwordx4 %0, %1, off"                 \
                 : "=&v"(dst)                                      \
                 : "v"(addr))

// ---- K1: read + LIF + pack (write only 8 MB) -------------------------------
__global__ __launch_bounds__(256) void lif_pack(const float* __restrict__ x,
                                                unsigned long long* __restrict__ ws,
                                                int n4) {
    int i = blockIdx.x * blockDim.x + threadIdx.x;
    if (i >= n4) return;

    const unsigned long long stride = (unsigned long long)n4 * 16ull;
    unsigned long long a = (unsigned long long)x + (unsigned long long)i * 16ull;

    vfloat4 x0, x1, x2, x3, x4, x5, x6, x7;
    ASM_LOAD(x0, a + 0 * stride);
    ASM_LOAD(x1, a + 1 * stride);
    ASM_LOAD(x2, a + 2 * stride);
    ASM_LOAD(x3, a + 3 * stride);
    ASM_LOAD(x4, a + 4 * stride);
    ASM_LOAD(x5, a + 5 * stride);
    ASM_LOAD(x6, a + 6 * stride);
    ASM_LOAD(x7, a + 7 * stride);
    asm volatile("s_waitcnt vmcnt(0)"
                 : "+v"(x0), "+v"(x1), "+v"(x2), "+v"(x3),
                   "+v"(x4), "+v"(x5), "+v"(x6), "+v"(x7));

    vfloat4 xs[T_STEPS] = {x0, x1, x2, x3, x4, x5, x6, x7};
    vfloat4 V = (vfloat4)(0.f);
    unsigned long long acc = 0ull;
#pragma unroll
    for (int t = 0; t < T_STEPS; ++t) {
        StepOut sa = lif_step(V.x, xs[t].x);
        StepOut sb = lif_step(V.y, xs[t].y);
        StepOut sc = lif_step(V.z, xs[t].z);
        StepOut sd = lif_step(V.w, xs[t].w);
        V.x = sa.V; V.y = sb.V; V.z = sc.V; V.w = sd.V;
        unsigned byte = enc(sa.o) | (enc(sb.o) << 2) | (enc(sc.o) << 4) | (enc(sd.o) << 6);
        acc |= ((unsigned long long)byte) << (8 * t);
    }
    ws[i] = acc;
}

// ---- K2: unpack + write 128 MB (fill-like, write-dominated) ----------------
__global__ __launch_bounds__(256) void lif_unpack(const unsigned long long* __restrict__ ws,
                                                  vfloat4* __restrict__ out,
                                                  int n4) {
    int i = blockIdx.x * blockDim.x + threadIdx.x;
    if (i >= n4) return;

    unsigned long long u = ws[i];
    const size_t s = (size_t)n4;
#pragma unroll
    for (int t = 0; t < T_STEPS; ++t) {
        unsigned byte = (unsigned)(u >> (8 * t)) & 0xFFu;
        vfloat4 o;
        o.x = dec(byte & 3u);
        o.y = dec((byte >> 2) & 3u);
        o.z = dec((byte >> 4) & 3u);
        o.w = dec((byte >> 6) & 3u);
        __builtin_nontemporal_store(o, &out[(size_t)t * s + i]);
    }
}

// ---- Fallback: best single-pass kernel (R7, 79 us) -------------------------
__device__ __forceinline__ vfloat4 lif_step4(vfloat4& V, vfloat4 xt) {
    StepOut a = lif_step(V.x, xt.x);
    StepOut b = lif_step(V.y, xt.y);
    StepOut c = lif_step(V.z, xt.z);
    StepOut d = lif_step(V.w, xt.w);
    vfloat4 Vn, o;
    Vn.x = a.V; Vn.y = b.V; Vn.z = c.V; Vn.w = d.V;
    o.x = a.o;  o.y = b.o;  o.z = c.o;  o.w = d.o;
    V = Vn;
    return o;
}

__global__ __launch_bounds__(256) void lif_single(const vfloat4* __restrict__ x,
                                                  vfloat4* __restrict__ out,
                                                  int n4) {
    const int Q = n4 >> 2;
    int q = blockIdx.x * blockDim.x + threadIdx.x;
    if (q >= Q) return;
    const size_t s = (size_t)n4;
    const size_t i0 = (size_t)q;
    const size_t i1 = (size_t)q + (size_t)Q;
    const size_t i2 = (size_t)q + 2 * (size_t)Q;
    const size_t i3 = (size_t)q + 3 * (size_t)Q;
    vfloat4 Va = (vfloat4)(0.f);
    vfloat4 Vb = Va, Vc = Va, Vd = Va;
#pragma unroll
    for (int t = 0; t < T_STEPS; ++t) {
        const size_t base = (size_t)t * s;
        vfloat4 xa = x[base + i0];
        vfloat4 xb = x[base + i1];
        vfloat4 xc = x[base + i2];
        vfloat4 xd = x[base + i3];
        vfloat4 oa = lif_step4(Va, xa);
        vfloat4 ob = lif_step4(Vb, xb);
        vfloat4 oc = lif_step4(Vc, xc);
        vfloat4 od = lif_step4(Vd, xd);
        __builtin_nontemporal_store(oa, &out[base + i0]);
        __builtin_nontemporal_store(ob, &out[base + i1]);
        __builtin_nontemporal_store(oc, &out[base + i2]);
        __builtin_nontemporal_store(od, &out[base + i3]);
    }
}

extern "C" void kernel_launch(void* const* d_in, const int* in_sizes, int n_in,
                              void* d_out, int out_size, void* d_ws, size_t ws_size,
                              hipStream_t stream) {
    const float* x = (const float*)d_in[0];
    float* out = (float*)d_out;

    int total = in_sizes[0];            // T*B*C*H*W = 33554432
    int n = total / T_STEPS;            // spatial elements per timestep
    int n4 = n / 4;                     // float4 groups = 1048576

    size_t need = (size_t)n4 * sizeof(unsigned long long);  // 8 MB
    dim3 block(256);
    dim3 grid((n4 + block.x - 1) / block.x);  // 4096 blocks

    if (ws_size >= need) {
        unsigned long long* ws = (unsigned long long*)d_ws;
        lif_pack<<<grid, block, 0, stream>>>(x, ws, n4);
        lif_unpack<<<grid, block, 0, stream>>>(ws, (vfloat4*)out, n4);
    } else {
        int Q = n4 / 4;
        dim3 grid1((Q + block.x - 1) / block.x);
        lif_single<<<grid1, block, 0, stream>>>((const vfloat4*)x, (vfloat4*)out, n4);
    }
}

// Round 10
// 232.663 us; speedup vs baseline: 1.0548x; 1.0548x over previous
//
#include <hip/hip_runtime.h>

// LIF neuron over [T, B, C, H, W] = [8, 32, 128, 32, 32] fp32.
// V_new = V + (-V/TAU + x_t); spike = (V_new>=1) - (V_new<=-1); hard reset.
//
// Evidence through R9: access-mode, not MLP, is what moves this kernel.
//   NT loads + NT stores (R6, 4-chain): ~69 us   <- best
//   cached loads + NT stores (R7):       79 us
//   cached asm loads (R8, R9-pack):      88-93 us
// Fills prove 6.5 TB/s writes; m13 float4 copy 6.3 TB/s combined.
// R10: retry phase separation with NT everywhere (R9's pack used cached
// loads — the slow path — so the idea was never tested):
//   K1 pack  (R6 structure, NT loads): read 134 MB, LIF, 2-bit spikes ->
//            4 coalesced u64 NT stores (8 MB).
//   K2 unpack (fill-like): 1 u64 NT load, 8 NT float4 stores (128 MB).
// Fallback = R6 kernel verbatim if ws too small.

#define T_STEPS 8

typedef float vfloat4 __attribute__((ext_vector_type(4)));
typedef unsigned long long u64;

struct StepOut { float V; float o; };

__device__ __forceinline__ StepOut lif_step(float V, float x) {
    const float TAU = (float)(5.0 / 3.0);  // fp32, matches np cast
    // Replicate reference op order exactly: neg, IEEE divide, add, add.
    float dv = (-V) / TAU + x;
    float Vn = V + dv;
    float o = (Vn >= 1.0f ? 1.0f : 0.0f) - (Vn <= -1.0f ? 1.0f : 0.0f);
    StepOut r;
    r.o = o;
    r.V = (o == 0.0f) ? Vn : 0.0f;  // o is exactly -1/0/+1
    return r;
}

__device__ __forceinline__ vfloat4 lif_step4(vfloat4& V, vfloat4 xt) {
    StepOut a = lif_step(V.x, xt.x);
    StepOut b = lif_step(V.y, xt.y);
    StepOut c = lif_step(V.z, xt.z);
    StepOut d = lif_step(V.w, xt.w);
    vfloat4 Vn, o;
    Vn.x = a.V; Vn.y = b.V; Vn.z = c.V; Vn.w = d.V;
    o.x = a.o;  o.y = b.o;  o.z = c.o;  o.w = d.o;
    V = Vn;
    return o;
}

__device__ __forceinline__ unsigned enc(float o) {
    // exact: o is one of {-1.f, 0.f, 1.f}
    return (o == 1.0f) ? 1u : ((o == -1.0f) ? 2u : 0u);
}

__device__ __forceinline__ unsigned enc4(vfloat4 o) {
    return enc(o.x) | (enc(o.y) << 2) | (enc(o.z) << 4) | (enc(o.w) << 6);
}

__device__ __forceinline__ float dec(unsigned c) {
    return (c == 1u) ? 1.0f : ((c == 2u) ? -1.0f : 0.0f);
}

// ---- K1: NT-read 134 MB + LIF + pack -> 8 MB NT write ----------------------
__global__ __launch_bounds__(256) void lif_pack(const vfloat4* __restrict__ x,
                                                u64* __restrict__ ws,
                                                int n4) {
    const int Q = n4 >> 2;
    int q = blockIdx.x * blockDim.x + threadIdx.x;
    if (q >= Q) return;

    const size_t s = (size_t)n4;
    const size_t i0 = (size_t)q;
    const size_t i1 = (size_t)q + (size_t)Q;
    const size_t i2 = (size_t)q + 2 * (size_t)Q;
    const size_t i3 = (size_t)q + 3 * (size_t)Q;

    vfloat4 Va = (vfloat4)(0.f);
    vfloat4 Vb = Va, Vc = Va, Vd = Va;
    u64 pa = 0, pb = 0, pc = 0, pd = 0;

#pragma unroll
    for (int t = 0; t < T_STEPS; ++t) {
        const size_t base = (size_t)t * s;
        vfloat4 xa = __builtin_nontemporal_load(&x[base + i0]);
        vfloat4 xb = __builtin_nontemporal_load(&x[base + i1]);
        vfloat4 xc = __builtin_nontemporal_load(&x[base + i2]);
        vfloat4 xd = __builtin_nontemporal_load(&x[base + i3]);

        vfloat4 oa = lif_step4(Va, xa);
        vfloat4 ob = lif_step4(Vb, xb);
        vfloat4 oc = lif_step4(Vc, xc);
        vfloat4 od = lif_step4(Vd, xd);

        pa |= ((u64)enc4(oa)) << (8 * t);
        pb |= ((u64)enc4(ob)) << (8 * t);
        pc |= ((u64)enc4(oc)) << (8 * t);
        pd |= ((u64)enc4(od)) << (8 * t);
    }
    // ws indexed by column id -> unpack reads linearly. Lane-coalesced 8B.
    __builtin_nontemporal_store(pa, &ws[i0]);
    __builtin_nontemporal_store(pb, &ws[i1]);
    __builtin_nontemporal_store(pc, &ws[i2]);
    __builtin_nontemporal_store(pd, &ws[i3]);
}

// ---- K2: fill-like expansion: 8 MB NT read -> 128 MB NT write --------------
__global__ __launch_bounds__(256) void lif_unpack(const u64* __restrict__ ws,
                                                  vfloat4* __restrict__ out,
                                                  int n4) {
    int i = blockIdx.x * blockDim.x + threadIdx.x;
    if (i >= n4) return;

    u64 u = __builtin_nontemporal_load(&ws[i]);
    const size_t s = (size_t)n4;
#pragma unroll
    for (int t = 0; t < T_STEPS; ++t) {
        unsigned byte = (unsigned)(u >> (8 * t)) & 0xFFu;
        vfloat4 o;
        o.x = dec(byte & 3u);
        o.y = dec((byte >> 2) & 3u);
        o.z = dec((byte >> 4) & 3u);
        o.w = dec((byte >> 6) & 3u);
        __builtin_nontemporal_store(o, &out[(size_t)t * s + i]);
    }
}

// ---- Fallback: R6 kernel (best single-pass, ~69 us) ------------------------
__global__ __launch_bounds__(256) void lif_single(const vfloat4* __restrict__ x,
                                                  vfloat4* __restrict__ out,
                                                  int n4) {
    const int Q = n4 >> 2;
    int q = blockIdx.x * blockDim.x + threadIdx.x;
    if (q >= Q) return;
    const size_t s = (size_t)n4;
    const size_t i0 = (size_t)q;
    const size_t i1 = (size_t)q + (size_t)Q;
    const size_t i2 = (size_t)q + 2 * (size_t)Q;
    const size_t i3 = (size_t)q + 3 * (size_t)Q;
    vfloat4 Va = (vfloat4)(0.f);
    vfloat4 Vb = Va, Vc = Va, Vd = Va;
#pragma unroll
    for (int t = 0; t < T_STEPS; ++t) {
        const size_t base = (size_t)t * s;
        vfloat4 xa = __builtin_nontemporal_load(&x[base + i0]);
        vfloat4 xb = __builtin_nontemporal_load(&x[base + i1]);
        vfloat4 xc = __builtin_nontemporal_load(&x[base + i2]);
        vfloat4 xd = __builtin_nontemporal_load(&x[base + i3]);
        vfloat4 oa = lif_step4(Va, xa);
        vfloat4 ob = lif_step4(Vb, xb);
        vfloat4 oc = lif_step4(Vc, xc);
        vfloat4 od = lif_step4(Vd, xd);
        __builtin_nontemporal_store(oa, &out[base + i0]);
        __builtin_nontemporal_store(ob, &out[base + i1]);
        __builtin_nontemporal_store(oc, &out[base + i2]);
        __builtin_nontemporal_store(od, &out[base + i3]);
    }
}

extern "C" void kernel_launch(void* const* d_in, const int* in_sizes, int n_in,
                              void* d_out, int out_size, void* d_ws, size_t ws_size,
                              hipStream_t stream) {
    const float* x = (const float*)d_in[0];
    float* out = (float*)d_out;

    int total = in_sizes[0];            // T*B*C*H*W = 33554432
    int n = total / T_STEPS;            // spatial elements per timestep
    int n4 = n / 4;                     // float4 groups = 1048576
    int Q = n4 / 4;                     // pack threads = 262144

    size_t need = (size_t)n4 * sizeof(u64);  // 8 MB
    dim3 block(256);

    if (ws_size >= need) {
        dim3 gridP((Q + block.x - 1) / block.x);   // 1024 blocks
        dim3 gridU((n4 + block.x - 1) / block.x);  // 4096 blocks
        u64* ws = (u64*)d_ws;
        lif_pack<<<gridP, block, 0, stream>>>((const vfloat4*)x, ws, n4);
        lif_unpack<<<gridU, block, 0, stream>>>(ws, (vfloat4*)out, n4);
    } else {
        dim3 grid1((Q + block.x - 1) / block.x);
        lif_single<<<grid1, block, 0, stream>>>((const vfloat4*)x, (vfloat4*)out, n4);
    }
}

// Round 11
// 225.745 us; speedup vs baseline: 1.0871x; 1.0306x over previous
//
#include <hip/hip_runtime.h>

// LIF neuron over [T, B, C, H, W] = [8, 32, 128, 32, 32] fp32.
// V_new = V + (-V/TAU + x_t); spike = (V_new>=1) - (V_new<=-1); hard reset.
//
// Evidence through R10:
//   - Writes stream at 6.5 TB/s (poison fills); reads cap at ~2.4-2.6 TB/s
//     in every structure tried (cached/NT/asm, 1-4 chains).
//   - R6 (NT ld/st, 4 col/thread, 1024 blocks, 16 waves/CU): ~70 us BEST.
//   - R10 phase separation (pack 60 + unpack 20): reads are the capped
//     resource; writes were already free under the read stream. Reverted.
//   - SDK D2D copy reads at ~3.15 TB/s -> ~25% read headroom exists.
// R11: R6 structure, but full occupancy: 2 columns/thread -> 2048 blocks =
// 8192 waves = 32 waves/CU (2x R6), plus explicit next-timestep register
// prefetch (~4 NT loads in flight per wave steady-state).

#define T_STEPS 8

typedef float vfloat4 __attribute__((ext_vector_type(4)));

struct StepOut { float V; float o; };

__device__ __forceinline__ StepOut lif_step(float V, float x) {
    const float TAU = (float)(5.0 / 3.0);  // fp32, matches np cast
    // Replicate reference op order exactly: neg, IEEE divide, add, add.
    float dv = (-V) / TAU + x;
    float Vn = V + dv;
    float o = (Vn >= 1.0f ? 1.0f : 0.0f) - (Vn <= -1.0f ? 1.0f : 0.0f);
    StepOut r;
    r.o = o;
    r.V = (o == 0.0f) ? Vn : 0.0f;  // o is exactly -1/0/+1
    return r;
}

__device__ __forceinline__ vfloat4 lif_step4(vfloat4& V, vfloat4 xt) {
    StepOut a = lif_step(V.x, xt.x);
    StepOut b = lif_step(V.y, xt.y);
    StepOut c = lif_step(V.z, xt.z);
    StepOut d = lif_step(V.w, xt.w);
    vfloat4 Vn, o;
    Vn.x = a.V; Vn.y = b.V; Vn.z = c.V; Vn.w = d.V;
    o.x = a.o;  o.y = b.o;  o.z = c.o;  o.w = d.o;
    V = Vn;
    return o;
}

__global__ __launch_bounds__(256) void lif_kernel(const vfloat4* __restrict__ x,
                                                  vfloat4* __restrict__ out,
                                                  int n4) {
    const int Q = n4 >> 1;  // 2 columns per thread
    int q = blockIdx.x * blockDim.x + threadIdx.x;
    if (q >= Q) return;

    const size_t s = (size_t)n4;
    const size_t i0 = (size_t)q;
    const size_t i1 = (size_t)q + (size_t)Q;

    vfloat4 Va = (vfloat4)(0.f);
    vfloat4 Vb = Va;

    // Prefetch t=0.
    vfloat4 xa = __builtin_nontemporal_load(&x[i0]);
    vfloat4 xb = __builtin_nontemporal_load(&x[i1]);

#pragma unroll
    for (int t = 0; t < T_STEPS; ++t) {
        const size_t base = (size_t)t * s;
        vfloat4 na, nb;
        if (t + 1 < T_STEPS) {
            // Next timestep's loads issue before this step's compute/stores;
            // compiler's precise vmcnt keeps ~4 loads in flight per wave.
            const size_t nbase = (size_t)(t + 1) * s;
            na = __builtin_nontemporal_load(&x[nbase + i0]);
            nb = __builtin_nontemporal_load(&x[nbase + i1]);
        }
        vfloat4 oa = lif_step4(Va, xa);
        vfloat4 ob = lif_step4(Vb, xb);
        __builtin_nontemporal_store(oa, &out[base + i0]);
        __builtin_nontemporal_store(ob, &out[base + i1]);
        if (t + 1 < T_STEPS) {
            xa = na;
            xb = nb;
        }
    }
}

extern "C" void kernel_launch(void* const* d_in, const int* in_sizes, int n_in,
                              void* d_out, int out_size, void* d_ws, size_t ws_size,
                              hipStream_t stream) {
    const float* x = (const float*)d_in[0];
    float* out = (float*)d_out;

    int total = in_sizes[0];            // T*B*C*H*W = 33554432
    int n = total / T_STEPS;            // spatial elements per timestep
    int n4 = n / 4;                     // float4 groups = 1048576
    int Q = n4 / 2;                     // threads = 524288

    dim3 block(256);
    dim3 grid((Q + block.x - 1) / block.x);  // 2048 blocks -> 32 waves/CU
    lif_kernel<<<grid, block, 0, stream>>>((const vfloat4*)x, (vfloat4*)out, n4);
}